// Round 9
// baseline (205.988 us; speedup 1.0000x reference)
//
#include <hip/hip_runtime.h>
#include <hip/hip_bf16.h>
#include <stdint.h>

// ---------------------------------------------------------------------------
// LinkPredictor: out = minmax_norm(E @ E^T)[block-diag strict upper triangle]
// N=16384 (128 graphs x 128), D=512.
// R19: m201-style fine-phase interleave on R18's 256x256 superblock.
// Evidence trail: R10-R18 varied conflicts, coalescing, occupancy, vmcnt,
// bytes/tile, HBM traffic -- k_gemm pinned at 92-97us, MfmaUtil ~33%, all
// pipes ~1/3 idle. Only invariant left: the coarse 1-phase-per-K-tile
// schedule. Catalog m233/m196/m248: that structure caps at ~25-35%;
// the fix is per-phase {ds_read || stage -> barrier -> lgkmcnt(0) ->
// dense MFMA cluster -> barrier} with counted vmcnt only at tile bounds.
// Here: 2 phases per BK=64 K-tile (one per ks: 6 ds_read_b128 + 2 stage
// instrs + 8 MFMA), 3 x 32KB LDS buffers, depth-2 prefetch (tile kt+2
// staged during kt, 2 instrs/phase), vmcnt(4) at tile boundary (vmcnt(0)
// at kt==6), raw s_barrier + sched_barrier(0) fences (R15-proven),
// s_setprio(1) around MFMA clusters (T5). Geometry, wrapped super-col map,
// granule layout (qswap/sfun: 0 conflicts, coalesced DMA), diag path,
// refine, convert, gather all byte-identical to R18 (passed).
// ---------------------------------------------------------------------------

typedef __attribute__((ext_vector_type(8))) __bf16 bf16x8;
typedef __attribute__((ext_vector_type(16))) float floatx16;
typedef __attribute__((ext_vector_type(4))) int intx4;
typedef __attribute__((ext_vector_type(16))) int intx16;

#define AS1 __attribute__((address_space(1)))
#define AS3 __attribute__((address_space(3)))

static constexpr int DIM      = 512;
static constexpr int SLOTX    = 40;         // grid x (mult of 8); x<33 i8, 33/34 diag
static constexpr int NSLOT    = SLOTX * 64; // refine slot space
static constexpr float QS     = 19.5f;      // i8 quant scale
static constexpr int MARGIN_I = 3042;       // 8 sims-units * QS^2

// ctrl: [0] fkey_min [1] fkey_max [2] i8 gmin

static __device__ __forceinline__ unsigned short f2bf_rne(float f) {
  unsigned int u = __float_as_uint(f);
  u += 0x7fffu + ((u >> 16) & 1u);
  return (unsigned short)(u >> 16);
}
static __device__ __forceinline__ int fkey(float f) {
  int s = __float_as_int(f);
  return s >= 0 ? s : (s ^ 0x7fffffff);
}
static __device__ __forceinline__ float funkey(int k) {
  return __int_as_float(k >= 0 ? k : (k ^ 0x7fffffff));
}
// bf16 tile, BK=128 (diag): 16 chunks(16B)/row
static __device__ __forceinline__ int swzd(int row, int c16) {
  return c16 ^ (row & 15);
}
// bf16 tile, BK=64 (refine): 8 chunks(16B)/row
static __device__ __forceinline__ int swz8(int row, int c8) {
  return c8 ^ (row & 7);
}
// i8 BK=64 plane layout helpers: q = swap bits 0,2 (involution)
static __device__ __forceinline__ int qswap(int v) {
  return (v & 0x7A) | ((v & 1) << 2) | ((v >> 2) & 1);
}
static __device__ __forceinline__ int sfun(int row) {
  return (row & 3) ^ ((row >> 3) & 3);
}

// ---- kernel 1: fp32 -> bf16 + i8, init ctrl --------------------------------
__global__ void k_convert(const float* __restrict__ in,
                          unsigned short* __restrict__ bf,
                          char* __restrict__ q,
                          int* __restrict__ ctrl, int n4) {
  int i = blockIdx.x * blockDim.x + threadIdx.x;
  if (i == 0) {
    ctrl[0] = 0x7fffffff; ctrl[1] = (int)0x80000000;
    ctrl[2] = 0x7fffffff;
  }
  if (i >= n4) return;
  float4 v = ((const float4*)in)[i];
  ushort4 o;
  o.x = f2bf_rne(v.x); o.y = f2bf_rne(v.y);
  o.z = f2bf_rne(v.z); o.w = f2bf_rne(v.w);
  ((ushort4*)bf)[i] = o;
  int qx = __float2int_rn(v.x * QS), qy = __float2int_rn(v.y * QS);
  int qz = __float2int_rn(v.z * QS), qw = __float2int_rn(v.w * QS);
  char4 c;
  c.x = (char)min(127, max(-127, qx));
  c.y = (char)min(127, max(-127, qy));
  c.z = (char)min(127, max(-127, qz));
  c.w = (char)min(127, max(-127, qw));
  ((char4*)q)[i] = c;
}

// ---- kernel 2: GEMM --------------------------------------------------------
// grid (40, 64) x 512 threads: x<33 -> i8 256x256 superblock (s=y, t=(y+x)&63);
// x in {33,34} -> bf16 exact diagonal tile tr = 2y + (x-33); x>34 -> pad.
__global__ __launch_bounds__(512, 2) void k_gemm(
    const char* __restrict__ Eq,
    const unsigned short* __restrict__ E,
    int* __restrict__ ipart,
    float* __restrict__ diagblocks,
    int* __restrict__ ctrl) {
  const int x = blockIdx.x;
  const int y = blockIdx.y;
  if (x > 34) return;                      // XCD-alignment padding
  const int pi = y * SLOTX + x;

  const int tid = threadIdx.x;
  // i8 path: 3 buffers x {A0,A1,B0,B1 planes of 8KB} = 96 KB.
  // Diag path reuses first 32 KB as one bf16 tile.
  __shared__ __align__(16) char smem[3][32768];
  __shared__ float2 redbuf[8];
  __shared__ int iredbuf[8];

  const int w = tid >> 6, lane = tid & 63;
  const int l31 = lane & 31;
  const int kg  = lane >> 5;

  if (x < 33) {
    const int tt = (y + x) & 63;          // super-col
    const int rA0 = 256 * y,  rA1 = 256 * y + 128;
    const int rB0 = 256 * tt, rB1 = 256 * tt + 128;

    // wave grid 4x2 over 256x256: wr in 0..3 (64-row slab), wc in 0..1
    // (128-col slab = one B plane). Per wave 64x128, acc[2][4] = 128 AGPR.
    const int wr = w >> 1, wc = w & 1;

    intx16 acc[2][4];
#pragma unroll
    for (int i = 0; i < 2; i++)
#pragma unroll
      for (int j = 0; j < 4; j++)
#pragma unroll
        for (int r = 0; r < 16; r++) acc[i][j][r] = 0;

    // Stage HALF a K-tile (2 of 4 planes) into buffer bb. h=0: A0,A1;
    // h=1: B0,B1. LDS dest linear (tid*16 within plane); plane granule
    // tid = qswap(row)*4 + (c4 ^ sfun(row)) -> row = qswap(tid>>2),
    // c4 = (tid&3)^sfun(row). Lanes 4k..4k+3 share one 64B global line.
#define STAGE2(bb, kt, h) do {                                                \
    int q_   = tid >> 2;                                                      \
    int row_ = qswap(q_);                                                     \
    int off_ = (kt) * 64 + (((tid & 3) ^ sfun(row_)) * 16);                   \
    char* d_ = smem[bb] + tid * 16;                                           \
    if ((h) == 0) {                                                           \
      __builtin_amdgcn_global_load_lds(                                       \
          (const AS1 unsigned int*)(Eq + (size_t)(rA0 + row_) * DIM + off_),  \
          (AS3 unsigned int*)d_, 16, 0, 0);                                   \
      __builtin_amdgcn_global_load_lds(                                       \
          (const AS1 unsigned int*)(Eq + (size_t)(rA1 + row_) * DIM + off_),  \
          (AS3 unsigned int*)(d_ + 8192), 16, 0, 0);                          \
    } else {                                                                  \
      __builtin_amdgcn_global_load_lds(                                       \
          (const AS1 unsigned int*)(Eq + (size_t)(rB0 + row_) * DIM + off_),  \
          (AS3 unsigned int*)(d_ + 16384), 16, 0, 0);                         \
      __builtin_amdgcn_global_load_lds(                                       \
          (const AS1 unsigned int*)(Eq + (size_t)(rB1 + row_) * DIM + off_),  \
          (AS3 unsigned int*)(d_ + 24576), 16, 0, 0);                         \
    }                                                                         \
  } while (0)

    // per-thread read offsets. A rows in [0,256): plane = ra>>7.
    const int ra0 = wr * 64 + l31, ra1 = wr * 64 + 32 + l31;
    const int pa0 = (ra0 >> 7) * 8192 + qswap(ra0 & 127) * 64, sa0 = sfun(ra0 & 127);
    const int pa1 = (ra1 >> 7) * 8192 + qswap(ra1 & 127) * 64, sa1 = sfun(ra1 & 127);
    // B cols (as rows of B plane): wc selects plane; 4 col-tiles of 32.
    const int rb0 = 0 * 32 + l31, rb1 = 1 * 32 + l31;
    const int rb2 = 2 * 32 + l31, rb3 = 3 * 32 + l31;
    const int pbB = 16384 + wc * 8192;
    const int pb0 = pbB + qswap(rb0) * 64, sb0 = sfun(rb0);
    const int pb1 = pbB + qswap(rb1) * 64, sb1 = sfun(rb1);
    const int pb2 = pbB + qswap(rb2) * 64, sb2 = sfun(rb2);
    const int pb3 = pbB + qswap(rb3) * 64, sb3 = sfun(rb3);

    // Prologue: tiles 0 and 1 fully in flight (8 instrs); complete tile 0
    // (vmcnt(4)), leave tile 1's 4 in flight across the barrier.
    STAGE2(0, 0, 0); STAGE2(0, 0, 1);
    STAGE2(1, 1, 0); STAGE2(1, 1, 1);
    asm volatile("s_waitcnt vmcnt(4)" ::: "memory");
    __builtin_amdgcn_s_barrier();
    __builtin_amdgcn_sched_barrier(0);

#pragma unroll
    for (int kt = 0; kt < 8; kt++) {               // K = 512 = 8 * BK(64)
      const char* cb = smem[kt % 3];
#pragma unroll
      for (int ks = 0; ks < 2; ks++) {             // 2 phases per K-tile
        // --- phase: ds_read subtile || stage 2 instrs of tile kt+2 ---
        const int c = ks * 2 + kg;
        intx4 af0 = *(const intx4*)(cb + pa0 + ((c ^ sa0) << 4));
        intx4 af1 = *(const intx4*)(cb + pa1 + ((c ^ sa1) << 4));
        intx4 b0  = *(const intx4*)(cb + pb0 + ((c ^ sb0) << 4));
        intx4 b1  = *(const intx4*)(cb + pb1 + ((c ^ sb1) << 4));
        intx4 b2  = *(const intx4*)(cb + pb2 + ((c ^ sb2) << 4));
        intx4 b3  = *(const intx4*)(cb + pb3 + ((c ^ sb3) << 4));
        if (kt + 2 < 8) STAGE2((kt + 2) % 3, kt + 2, ks);
        __builtin_amdgcn_s_barrier();
        asm volatile("s_waitcnt lgkmcnt(0)" ::: "memory");
        __builtin_amdgcn_sched_barrier(0);
        __builtin_amdgcn_s_setprio(1);
        acc[0][0] = __builtin_amdgcn_mfma_i32_32x32x32_i8(af0, b0, acc[0][0], 0, 0, 0);
        acc[0][1] = __builtin_amdgcn_mfma_i32_32x32x32_i8(af0, b1, acc[0][1], 0, 0, 0);
        acc[0][2] = __builtin_amdgcn_mfma_i32_32x32x32_i8(af0, b2, acc[0][2], 0, 0, 0);
        acc[0][3] = __builtin_amdgcn_mfma_i32_32x32x32_i8(af0, b3, acc[0][3], 0, 0, 0);
        acc[1][0] = __builtin_amdgcn_mfma_i32_32x32x32_i8(af1, b0, acc[1][0], 0, 0, 0);
        acc[1][1] = __builtin_amdgcn_mfma_i32_32x32x32_i8(af1, b1, acc[1][1], 0, 0, 0);
        acc[1][2] = __builtin_amdgcn_mfma_i32_32x32x32_i8(af1, b2, acc[1][2], 0, 0, 0);
        acc[1][3] = __builtin_amdgcn_mfma_i32_32x32x32_i8(af1, b3, acc[1][3], 0, 0, 0);
        __builtin_amdgcn_s_setprio(0);
        __builtin_amdgcn_sched_barrier(0);
        if (ks == 1) {
          // tile boundary: make buffer (kt+1)%3 ready. Outstanding:
          // kt<6: t(kt+1) 4 + t(kt+2) 4 -> vmcnt(4) completes t(kt+1).
          // kt==6: only t7's 4 -> vmcnt(0). kt==7: nothing to wait.
          if (kt < 6)       { asm volatile("s_waitcnt vmcnt(4)" ::: "memory"); }
          else if (kt == 6) { asm volatile("s_waitcnt vmcnt(0)" ::: "memory"); }
        }
        __builtin_amdgcn_s_barrier();
        __builtin_amdgcn_sched_barrier(0);
      }
    }
#undef STAGE2

    int vmin = 0x7fffffff;
#pragma unroll
    for (int ti = 0; ti < 2; ti++)
#pragma unroll
      for (int tj = 0; tj < 4; tj++)
#pragma unroll
        for (int r = 0; r < 16; r++) vmin = min(vmin, acc[ti][tj][r]);
#pragma unroll
    for (int m_ = 32; m_ >= 1; m_ >>= 1)
      vmin = min(vmin, __shfl_xor(vmin, m_));
    if (lane == 0) iredbuf[w] = vmin;
    __syncthreads();
    if (tid == 0) {
      int mn = iredbuf[0];
      for (int i = 1; i < 8; i++) mn = min(mn, iredbuf[i]);
      ipart[pi] = mn;
      atomicMin(&ctrl[2], mn);
    }
  } else {
    // ---- bf16 diagonal path (exact), BK=128, 32 KB of smem, 8 waves ----
    if (tid == 0) ipart[pi] = 0x7fffffff;        // never flagged
    const int tr = 2 * y + (x - 33);
    unsigned short* lA = (unsigned short*)&smem[0][0];
    // per-wave 64x32: wr = w>>2 row half, wcq = w&3 col 32-quarter
    const int wr = w >> 2, wcq = w & 3;
    floatx16 acc[2];
#pragma unroll
    for (int t = 0; t < 2; t++)
#pragma unroll
      for (int r = 0; r < 16; r++) acc[t][r] = 0.f;

    const int rowBase = tr * 128;

    for (int kb = 0; kb < 4; kb++) {
      const int kBase = kb * 128;
#pragma unroll
      for (int j = 0; j < 4; j++) {
        int p   = j * 512 + tid;                  // 0..2047 chunk id
        int row = p >> 4, c16 = p & 15;
        int sc = swzd(row, c16);
        const unsigned short* gA =
            E + (size_t)(rowBase + row) * DIM + kBase + sc * 8;
        __builtin_amdgcn_global_load_lds((const AS1 unsigned int*)gA,
                                         (AS3 unsigned int*)(lA + p * 8), 16, 0, 0);
      }
      __syncthreads();

#pragma unroll
      for (int ks = 0; ks < 8; ks++) {
        bf16x8 af[2], bfv;
        const int c16 = ks * 2 + kg;
#pragma unroll
        for (int t = 0; t < 2; t++) {
          int ra = wr * 64 + t * 32 + l31;
          af[t]  = *(const bf16x8*)(lA + ra * 128 + swzd(ra, c16) * 8);
        }
        {
          int rb = wcq * 32 + l31;
          bfv = *(const bf16x8*)(lA + rb * 128 + swzd(rb, c16) * 8);
        }
#pragma unroll
        for (int t = 0; t < 2; t++)
          acc[t] = __builtin_amdgcn_mfma_f32_32x32x16_bf16(
              af[t], bfv, acc[t], 0, 0, 0);
      }
      __syncthreads();
    }

    float vmin = 3.4e38f, vmax = -3.4e38f;
#pragma unroll
    for (int t = 0; t < 2; t++)
#pragma unroll
      for (int r = 0; r < 16; r++) {
        float v = acc[t][r];
        vmin = fminf(vmin, v);
        vmax = fmaxf(vmax, v);
      }
#pragma unroll
    for (int m_ = 32; m_ >= 1; m_ >>= 1) {
      vmin = fminf(vmin, __shfl_xor(vmin, m_));
      vmax = fmaxf(vmax, __shfl_xor(vmax, m_));
    }
    if (lane == 0) redbuf[w] = make_float2(vmin, vmax);
    __syncthreads();
    if (tid == 0) {
      float mn = redbuf[0].x, mx = redbuf[0].y;
      for (int i = 1; i < 8; i++) {
        mn = fminf(mn, redbuf[i].x);
        mx = fmaxf(mx, redbuf[i].y);
      }
      atomicMin(&ctrl[0], fkey(mn));
      atomicMax(&ctrl[1], fkey(mx));  // global max is diagonal (Cauchy-Schwarz)
    }

    float* Bout = diagblocks + (size_t)tr * (128 * 128);
    const int cbase = wcq * 32 + l31;             // C/D: col = lane & 31
#pragma unroll
    for (int t = 0; t < 2; t++) {
#pragma unroll
      for (int r = 0; r < 16; r++) {
        int row = wr * 64 + t * 32 + (r & 3) + 8 * (r >> 2) + 4 * kg;
        Bout[row * 128 + cbase] = acc[t][r];
      }
    }
  }
}

// ---- kernel 3: self-flagged bf16 refine (exact min of flagged superblocks) -
__global__ __launch_bounds__(256) void k_refine(
    const unsigned short* __restrict__ E,
    const int* __restrict__ ipart, int* __restrict__ ctrl) {
  const int pi = blockIdx.x;
  if (ipart[pi] > ctrl[2] + MARGIN_I) return;     // block-uniform
  const int y = pi / SLOTX, x = pi % SLOTX;
  if (x >= 33) return;                            // diag slots: exact already
  const int tt = (y + x) & 63;

  const int tid = threadIdx.x;
  __shared__ __align__(16) unsigned short lA[128 * 64];
  __shared__ __align__(16) unsigned short lB[128 * 64];
  __shared__ float redbuf[4];

  const int w = tid >> 6, lane = tid & 63;
  const int wr = w >> 1, wc = w & 1;
  const int l31 = lane & 31;
  const int kg  = lane >> 5;

  // recompute the superblock's 4 sub-tiles exactly (dups with diag path OK)
  for (int ab = 0; ab < 4; ab++) {
    const int rowBaseA = (2 * y + (ab >> 1)) * 128;
    const int rowBaseB = (2 * tt + (ab & 1)) * 128;

    floatx16 acc[2][2];
#pragma unroll
    for (int i = 0; i < 2; i++)
#pragma unroll
      for (int j = 0; j < 2; j++)
#pragma unroll
        for (int r = 0; r < 16; r++) acc[i][j][r] = 0.f;

    for (int kb = 0; kb < 8; kb++) {              // BK=64
      const int kBase = kb * 64;
#pragma unroll
      for (int j = 0; j < 4; j++) {
        int cb  = (w * 4 + j) * 64;
        int p   = cb + lane;
        int row = p >> 3, c8 = p & 7;
        int sc8 = swz8(row, c8);
        const unsigned short* gA = E + (size_t)(rowBaseA + row) * DIM + kBase + sc8 * 8;
        const unsigned short* gB = E + (size_t)(rowBaseB + row) * DIM + kBase + sc8 * 8;
        __builtin_amdgcn_global_load_lds((const AS1 unsigned int*)gA,
                                         (AS3 unsigned int*)(lA + cb * 8), 16, 0, 0);
        __builtin_amdgcn_global_load_lds((const AS1 unsigned int*)gB,
                                         (AS3 unsigned int*)(lB + cb * 8), 16, 0, 0);
      }
      __syncthreads();

#pragma unroll
      for (int ks = 0; ks < 4; ks++) {
        bf16x8 af[2], bfv[2];
        const int c8 = ks * 2 + kg;
#pragma unroll
        for (int t = 0; t < 2; t++) {
          int ra = wr * 64 + t * 32 + l31;
          int rb = wc * 64 + t * 32 + l31;
          af[t]  = *(const bf16x8*)(lA + (ra * 8 + swz8(ra, c8)) * 8);
          bfv[t] = *(const bf16x8*)(lB + (rb * 8 + swz8(rb, c8)) * 8);
        }
#pragma unroll
        for (int ti = 0; ti < 2; ti++)
#pragma unroll
          for (int tj = 0; tj < 2; tj++)
            acc[ti][tj] = __builtin_amdgcn_mfma_f32_32x32x16_bf16(
                af[ti], bfv[tj], acc[ti][tj], 0, 0, 0);
      }
      __syncthreads();
    }

    float vmin = 3.4e38f;
#pragma unroll
    for (int ti = 0; ti < 2; ti++)
#pragma unroll
      for (int tj = 0; tj < 2; tj++)
#pragma unroll
        for (int r = 0; r < 16; r++) vmin = fminf(vmin, acc[ti][tj][r]);
#pragma unroll
    for (int m_ = 32; m_ >= 1; m_ >>= 1)
      vmin = fminf(vmin, __shfl_xor(vmin, m_));
    if (lane == 0) redbuf[w] = vmin;
    __syncthreads();
    if (tid == 0) {
      float mn = redbuf[0];
      for (int i = 1; i < 4; i++) mn = fminf(mn, redbuf[i]);
      atomicMin(&ctrl[0], fkey(mn));
    }
    __syncthreads();
  }
}

// ---- kernel 4: gather + normalize ------------------------------------------
__global__ __launch_bounds__(256) void k_gather(
    const int* __restrict__ rix, const int* __restrict__ cix,
    const float* __restrict__ blocks, const int* __restrict__ ctrl,
    float* __restrict__ out, int n) {
  int i = blockIdx.x * blockDim.x + threadIdx.x;
  if (i >= n) return;
  float m   = funkey(ctrl[0]);
  float M   = funkey(ctrl[1]);
  float inv = 1.0f / (M - m + 1e-7f);
  int r = rix[i], c = cix[i];
  int g = r >> 7;
  float v = blocks[((size_t)g << 14) + ((r & 127) << 7) + (c & 127)];
  out[i] = (v - m) * inv;
}

// ---------------------------------------------------------------------------
extern "C" void kernel_launch(void* const* d_in, const int* in_sizes, int n_in,
                              void* d_out, int out_size, void* d_ws, size_t ws_size,
                              hipStream_t stream) {
  const float* emb = (const float*)d_in[0];
  const int* rix   = (const int*)d_in[1];
  const int* cix   = (const int*)d_in[2];

  char* ws = (char*)d_ws;
  int* ctrl           = (int*)ws;                            // 12 B (pad 256)
  unsigned short* Ebf = (unsigned short*)(ws + 256);         // 16 MB
  char* Eq            = (char*)(ws + 256 + (16u << 20));     // 8 MB
  float* diagblocks   = (float*)(ws + 256 + (24u << 20));    // 8 MB
  int* ipart          = (int*)(ws + 256 + (32u << 20));      // 10 KB
  int n4 = in_sizes[0] / 4;            // 16384*512 / 4

  k_convert<<<(n4 + 255) / 256, 256, 0, stream>>>(emb, Ebf, Eq, ctrl, n4);

  k_gemm<<<dim3(SLOTX, 64), 512, 0, stream>>>(Eq, Ebf, ipart, diagblocks, ctrl);

  k_refine<<<NSLOT, 256, 0, stream>>>(Ebf, ipart, ctrl);

  k_gather<<<(out_size + 255) / 256, 256, 0, stream>>>(rix, cix, diagblocks,
                                                       ctrl, (float*)d_out,
                                                       out_size);
}

// Round 11
// 192.041 us; speedup vs baseline: 1.0726x; 1.0726x over previous
//
#include <hip/hip_runtime.h>
#include <hip/hip_bf16.h>
#include <stdint.h>

// ---------------------------------------------------------------------------
// LinkPredictor: out = minmax_norm(E @ E^T)[block-diag strict upper triangle]
// N=16384 (128 graphs x 128), D=512.
// R21: revert to R17 (best measured passing config, 190.67us).
// R20's fp4 screen failed on a launch-config bug (n8 = size/32 instead of /8
// -> 3/4 of Ebf stale -> diag path garbage), and re-derived screen economics
// show fp4 is unviable regardless: fp4 dot noise sigma ~5.7 sims vs block-min
// spread 4.8 -> safe margin flags ~45% of superblocks -> refine eats the 2x
// MFMA win. i8 (sigma ~0.5 sims) is the screen-precision sweet spot.
// Evidence across R10-R20: k_gemm pinned at ~92us through changes in LDS
// conflicts, DMA coalescing, overlap schedule, counted vmcnt, setprio,
// occupancy (x2), staged bytes (+-33%), HBM traffic (x3.6), tile shape,
// and fine-phase scheduling. This is the documented 2-phase structural
// plateau (MfmaUtil ~33%). R17 config: pair-strip 128x256 i8 blocks,
// 8 waves x 64x64 (acc 64 AGPR, launch_bounds(512,4), 16 waves/CU),
// R14 granule map (0 bank conflicts both sides, coalesced DMA),
// 2-phase issue-early K-loop. Diag bf16 exact path; i8-flagged bf16
// refine; convert/gather unchanged.
// ---------------------------------------------------------------------------

typedef __attribute__((ext_vector_type(8))) __bf16 bf16x8;
typedef __attribute__((ext_vector_type(16))) float floatx16;
typedef __attribute__((ext_vector_type(4))) int intx4;
typedef __attribute__((ext_vector_type(16))) int intx16;

#define AS1 __attribute__((address_space(1)))
#define AS3 __attribute__((address_space(3)))

static constexpr int DIM      = 512;
static constexpr int NTILE    = 128;
static constexpr int GX       = 72;         // padded grid x (multiple of 8)
static constexpr int NPAIRIDX = 65 * 128;   // pair-slot space (x=64 -> diag)
static constexpr float QS     = 19.5f;      // i8 quant scale
static constexpr int MARGIN_I = 3042;       // 8 sims-units * QS^2

// ctrl: [0] fkey_min [1] fkey_max [2] i8 gmin

static __device__ __forceinline__ unsigned short f2bf_rne(float f) {
  unsigned int u = __float_as_uint(f);
  u += 0x7fffu + ((u >> 16) & 1u);
  return (unsigned short)(u >> 16);
}
static __device__ __forceinline__ int fkey(float f) {
  int s = __float_as_int(f);
  return s >= 0 ? s : (s ^ 0x7fffffff);
}
static __device__ __forceinline__ float funkey(int k) {
  return __int_as_float(k >= 0 ? k : (k ^ 0x7fffffff));
}
// bf16 tile, BK=128 (diag): 16 chunks(16B)/row
static __device__ __forceinline__ int swzd(int row, int c16) {
  return c16 ^ (row & 15);
}
// bf16 tile, BK=64 (refine): 8 chunks(16B)/row
static __device__ __forceinline__ int swz8(int row, int c8) {
  return c8 ^ (row & 7);
}
// i8 BK=64 layout helpers: q = swap bits 0,2 (involution)
static __device__ __forceinline__ int qswap(int v) {
  return (v & 0x7A) | ((v & 1) << 2) | ((v >> 2) & 1);
}
static __device__ __forceinline__ int sfun(int row) {
  return (row & 3) ^ ((row >> 3) & 3);
}

// ---- kernel 1: fp32 -> bf16 + i8, init ctrl --------------------------------
__global__ void k_convert(const float* __restrict__ in,
                          unsigned short* __restrict__ bf,
                          char* __restrict__ q,
                          int* __restrict__ ctrl, int n4) {
  int i = blockIdx.x * blockDim.x + threadIdx.x;
  if (i == 0) {
    ctrl[0] = 0x7fffffff; ctrl[1] = (int)0x80000000;
    ctrl[2] = 0x7fffffff;
  }
  if (i >= n4) return;
  float4 v = ((const float4*)in)[i];
  ushort4 o;
  o.x = f2bf_rne(v.x); o.y = f2bf_rne(v.y);
  o.z = f2bf_rne(v.z); o.w = f2bf_rne(v.w);
  ((ushort4*)bf)[i] = o;
  int qx = __float2int_rn(v.x * QS), qy = __float2int_rn(v.y * QS);
  int qz = __float2int_rn(v.z * QS), qw = __float2int_rn(v.w * QS);
  char4 c;
  c.x = (char)min(127, max(-127, qx));
  c.y = (char)min(127, max(-127, qy));
  c.z = (char)min(127, max(-127, qz));
  c.w = (char)min(127, max(-127, qw));
  ((char4*)q)[i] = c;
}

// ---- kernel 2: GEMM --------------------------------------------------------
// grid (72, 128) x 512 threads: x<64 -> i8 pair strip 128x256 at
// (tr=y, tc={2x,2x+1}); x==64 -> bf16 exact diagonal tile tr; x>64 -> pad.
__global__ __launch_bounds__(512, 4) void k_gemm(
    const char* __restrict__ Eq,
    const unsigned short* __restrict__ E,
    int* __restrict__ ipart,
    float* __restrict__ diagblocks,
    int* __restrict__ ctrl) {
  const int x  = blockIdx.x;
  const int tr = blockIdx.y;
  if (x > 64) return;                      // XCD-alignment padding
  const int pi = tr * 65 + x;

  const int tid = threadIdx.x;
  // i8 path: 2 buffers x {A[8KB], B0[8KB], B1[8KB]} = 48 KB.
  // Diag path reuses first 32 KB as one bf16 tile.
  __shared__ __align__(16) char smem[2][24576];
  __shared__ float2 redbuf[8];
  __shared__ int iredbuf[8];

  const int w = tid >> 6, lane = tid & 63;
  const int l31 = lane & 31;
  const int kg  = lane >> 5;

  if (x < 64) {
    const int tc1 = 2 * x + 1;
    if (tc1 <= tr) {                 // pair entirely at/below diagonal
      if (tid == 0) ipart[pi] = 0x7fffffff;
      return;
    }
    const int tc0 = (2 * x > tr) ? 2 * x : tc1;   // dup tc1 if tc0 not off-diag

    const int rowA  = tr  * 128;
    const int rowB0 = tc0 * 128;
    const int rowB1 = tc1 * 128;

    // 8-wave decomposition of the 128x256 output: wr = w>>2 (row half),
    // wc = w&3 (64-col quarter; wc>>1 selects B plane, wc&1 the half inside).
    const int wr = w >> 2;
    const int wcq = w & 3;
    const int bplane = 8192 + (wcq >> 1) * 8192;   // B0 or B1 plane offset

    intx16 acc[2][2];                // 64 AGPR
#pragma unroll
    for (int i = 0; i < 2; i++)
#pragma unroll
      for (int j = 0; j < 2; j++)
#pragma unroll
        for (int r = 0; r < 16; r++) acc[i][j][r] = 0;

    // Stage one BK=64 K-tile (A,B0,B1) into buffer bb: 3 loads/thread
    // (512 threads = exactly one 8KB plane each). LDS dest linear (p*16).
    // Granule p = qswap(row)*4 + (c4 ^ sfun(row)): quad q_=p>>2 -> row =
    // qswap(q_) (involution), c4 = (p&3)^sfun(row). Lanes 4k..4k+3 share a
    // row -> one 64B global line per quad (coalesced); bank signature =
    // R10's measured-zero pattern on the read side.
#define STAGE3(bb, kt) do {                                                   \
    int p_   = tid;                                                           \
    int q_   = p_ >> 2;                                                       \
    int row_ = qswap(q_);                                                     \
    int off_ = (kt) * 64 + (((p_ & 3) ^ sfun(row_)) * 16);                    \
    char* d_ = smem[bb] + p_ * 16;                                            \
    __builtin_amdgcn_global_load_lds(                                         \
        (const AS1 unsigned int*)(Eq + (size_t)(rowA + row_) * DIM + off_),   \
        (AS3 unsigned int*)d_, 16, 0, 0);                                     \
    __builtin_amdgcn_global_load_lds(                                         \
        (const AS1 unsigned int*)(Eq + (size_t)(rowB0 + row_) * DIM + off_),  \
        (AS3 unsigned int*)(d_ + 8192), 16, 0, 0);                            \
    __builtin_amdgcn_global_load_lds(                                         \
        (const AS1 unsigned int*)(Eq + (size_t)(rowB1 + row_) * DIM + off_),  \
        (AS3 unsigned int*)(d_ + 16384), 16, 0, 0);                           \
  } while (0)

    const int ra0 = wr * 64 + l31,        ra1 = wr * 64 + 32 + l31;
    const int rb0 = (wcq & 1) * 64 + l31, rb1 = (wcq & 1) * 64 + 32 + l31;
    // per-thread read offsets: byte addr = qswap(row)*64 + ((c4^sfun(row))<<4)
    const int pa0 = qswap(ra0) * 64, sa0 = sfun(ra0);
    const int pa1 = qswap(ra1) * 64, sa1 = sfun(ra1);
    const int pb0 = qswap(rb0) * 64, sb0 = sfun(rb0);
    const int pb1 = qswap(rb1) * 64, sb1 = sfun(rb1);

    STAGE3(0, 0);
    __syncthreads();

#pragma unroll
    for (int kt = 0; kt < 8; kt++) {               // K = 512 = 8 * BK(64)
      // Issue next tile's loads FIRST - they fly during this tile's compute.
      if (kt + 1 < 8) STAGE3((kt + 1) & 1, kt + 1);
      const char* cb = smem[kt & 1];
#pragma unroll
      for (int ks = 0; ks < 2; ks++) {             // 2 k-steps of 32
        const int c = ks * 2 + kg;
        intx4 af0 = *(const intx4*)(cb +           pa0 + ((c ^ sa0) << 4));
        intx4 af1 = *(const intx4*)(cb +           pa1 + ((c ^ sa1) << 4));
        intx4 bf0 = *(const intx4*)(cb + bplane +  pb0 + ((c ^ sb0) << 4));
        intx4 bf1 = *(const intx4*)(cb + bplane +  pb1 + ((c ^ sb1) << 4));
        acc[0][0] = __builtin_amdgcn_mfma_i32_32x32x32_i8(af0, bf0, acc[0][0], 0, 0, 0);
        acc[0][1] = __builtin_amdgcn_mfma_i32_32x32x32_i8(af0, bf1, acc[0][1], 0, 0, 0);
        acc[1][0] = __builtin_amdgcn_mfma_i32_32x32x32_i8(af1, bf0, acc[1][0], 0, 0, 0);
        acc[1][1] = __builtin_amdgcn_mfma_i32_32x32x32_i8(af1, bf1, acc[1][1], 0, 0, 0);
      }
      __syncthreads();
    }
#undef STAGE3

    int vmin = 0x7fffffff;
#pragma unroll
    for (int ti = 0; ti < 2; ti++)
#pragma unroll
      for (int tj = 0; tj < 2; tj++)
#pragma unroll
        for (int r = 0; r < 16; r++) vmin = min(vmin, acc[ti][tj][r]);
#pragma unroll
    for (int m_ = 32; m_ >= 1; m_ >>= 1)
      vmin = min(vmin, __shfl_xor(vmin, m_));
    if (lane == 0) iredbuf[w] = vmin;
    __syncthreads();
    if (tid == 0) {
      int mn = iredbuf[0];
      for (int i = 1; i < 8; i++) mn = min(mn, iredbuf[i]);
      ipart[pi] = mn;
      atomicMin(&ctrl[2], mn);
    }
  } else {
    // ---- bf16 diagonal path (exact), BK=128, 32 KB of smem, 8 waves ----
    if (tid == 0) ipart[pi] = 0x7fffffff;        // never flagged
    unsigned short* lA = (unsigned short*)&smem[0][0];
    // per-wave 64x32: wr = w>>2 row half, wcq = w&3 col 32-quarter
    const int wr = w >> 2, wcq = w & 3;
    floatx16 acc[2];
#pragma unroll
    for (int t = 0; t < 2; t++)
#pragma unroll
      for (int r = 0; r < 16; r++) acc[t][r] = 0.f;

    const int rowBase = tr * 128;

    for (int kb = 0; kb < 4; kb++) {
      const int kBase = kb * 128;
#pragma unroll
      for (int j = 0; j < 4; j++) {
        int p   = j * 512 + tid;                  // 0..2047 chunk id
        int row = p >> 4, c16 = p & 15;
        int sc = swzd(row, c16);
        const unsigned short* gA =
            E + (size_t)(rowBase + row) * DIM + kBase + sc * 8;
        __builtin_amdgcn_global_load_lds((const AS1 unsigned int*)gA,
                                         (AS3 unsigned int*)(lA + p * 8), 16, 0, 0);
      }
      __syncthreads();

#pragma unroll
      for (int ks = 0; ks < 8; ks++) {
        bf16x8 af[2], bfv;
        const int c16 = ks * 2 + kg;
#pragma unroll
        for (int t = 0; t < 2; t++) {
          int ra = wr * 64 + t * 32 + l31;
          af[t]  = *(const bf16x8*)(lA + ra * 128 + swzd(ra, c16) * 8);
        }
        {
          int rb = wcq * 32 + l31;
          bfv = *(const bf16x8*)(lA + rb * 128 + swzd(rb, c16) * 8);
        }
#pragma unroll
        for (int t = 0; t < 2; t++)
          acc[t] = __builtin_amdgcn_mfma_f32_32x32x16_bf16(
              af[t], bfv, acc[t], 0, 0, 0);
      }
      __syncthreads();
    }

    float vmin = 3.4e38f, vmax = -3.4e38f;
#pragma unroll
    for (int t = 0; t < 2; t++)
#pragma unroll
      for (int r = 0; r < 16; r++) {
        float v = acc[t][r];
        vmin = fminf(vmin, v);
        vmax = fmaxf(vmax, v);
      }
#pragma unroll
    for (int m_ = 32; m_ >= 1; m_ >>= 1) {
      vmin = fminf(vmin, __shfl_xor(vmin, m_));
      vmax = fmaxf(vmax, __shfl_xor(vmax, m_));
    }
    if (lane == 0) redbuf[w] = make_float2(vmin, vmax);
    __syncthreads();
    if (tid == 0) {
      float mn = redbuf[0].x, mx = redbuf[0].y;
      for (int i = 1; i < 8; i++) {
        mn = fminf(mn, redbuf[i].x);
        mx = fmaxf(mx, redbuf[i].y);
      }
      atomicMin(&ctrl[0], fkey(mn));
      atomicMax(&ctrl[1], fkey(mx));  // global max is diagonal (Cauchy-Schwarz)
    }

    float* Bout = diagblocks + (size_t)tr * (128 * 128);
    const int cbase = wcq * 32 + l31;             // C/D: col = lane & 31
#pragma unroll
    for (int t = 0; t < 2; t++) {
#pragma unroll
      for (int r = 0; r < 16; r++) {
        int row = wr * 64 + t * 32 + (r & 3) + 8 * (r >> 2) + 4 * kg;
        Bout[row * 128 + cbase] = acc[t][r];
      }
    }
  }
}

// ---- kernel 3: self-flagged bf16 refine (exact min of flagged pairs) -------
__global__ __launch_bounds__(256) void k_refine(
    const unsigned short* __restrict__ E,
    const int* __restrict__ ipart, int* __restrict__ ctrl) {
  const int pi = blockIdx.x;
  if (ipart[pi] > ctrl[2] + MARGIN_I) return;     // block-uniform
  const int tr = pi / 65, x = pi % 65;
  if (x == 64) return;                            // diag: exact already

  const int tid = threadIdx.x;
  __shared__ __align__(16) unsigned short lA[128 * 64];
  __shared__ __align__(16) unsigned short lB[128 * 64];
  __shared__ float redbuf[4];

  const int w = tid >> 6, lane = tid & 63;
  const int wr = w >> 1, wc = w & 1;
  const int l31 = lane & 31;
  const int kg  = lane >> 5;

  for (int s = 0; s < 2; s++) {
    const int tc = 2 * x + s;
    if (tc <= tr) continue;

    floatx16 acc[2][2];
#pragma unroll
    for (int i = 0; i < 2; i++)
#pragma unroll
      for (int j = 0; j < 2; j++)
#pragma unroll
        for (int r = 0; r < 16; r++) acc[i][j][r] = 0.f;

    const int rowBaseA = tr * 128;
    const int rowBaseB = tc * 128;

    for (int kb = 0; kb < 8; kb++) {              // BK=64
      const int kBase = kb * 64;
#pragma unroll
      for (int j = 0; j < 4; j++) {
        int cb  = (w * 4 + j) * 64;
        int p   = cb + lane;
        int row = p >> 3, c8 = p & 7;
        int sc8 = swz8(row, c8);
        const unsigned short* gA = E + (size_t)(rowBaseA + row) * DIM + kBase + sc8 * 8;
        const unsigned short* gB = E + (size_t)(rowBaseB + row) * DIM + kBase + sc8 * 8;
        __builtin_amdgcn_global_load_lds((const AS1 unsigned int*)gA,
                                         (AS3 unsigned int*)(lA + cb * 8), 16, 0, 0);
        __builtin_amdgcn_global_load_lds((const AS1 unsigned int*)gB,
                                         (AS3 unsigned int*)(lB + cb * 8), 16, 0, 0);
      }
      __syncthreads();

#pragma unroll
      for (int ks = 0; ks < 4; ks++) {
        bf16x8 af[2], bfv[2];
        const int c8 = ks * 2 + kg;
#pragma unroll
        for (int t = 0; t < 2; t++) {
          int ra = wr * 64 + t * 32 + l31;
          int rb = wc * 64 + t * 32 + l31;
          af[t]  = *(const bf16x8*)(lA + (ra * 8 + swz8(ra, c8)) * 8);
          bfv[t] = *(const bf16x8*)(lB + (rb * 8 + swz8(rb, c8)) * 8);
        }
#pragma unroll
        for (int ti = 0; ti < 2; ti++)
#pragma unroll
          for (int tj = 0; tj < 2; tj++)
            acc[ti][tj] = __builtin_amdgcn_mfma_f32_32x32x16_bf16(
                af[ti], bfv[tj], acc[ti][tj], 0, 0, 0);
      }
      __syncthreads();
    }

    float vmin = 3.4e38f;
#pragma unroll
    for (int ti = 0; ti < 2; ti++)
#pragma unroll
      for (int tj = 0; tj < 2; tj++)
#pragma unroll
        for (int r = 0; r < 16; r++) vmin = fminf(vmin, acc[ti][tj][r]);
#pragma unroll
    for (int m_ = 32; m_ >= 1; m_ >>= 1)
      vmin = fminf(vmin, __shfl_xor(vmin, m_));
    if (lane == 0) redbuf[w] = vmin;
    __syncthreads();
    if (tid == 0) {
      float mn = redbuf[0];
      for (int i = 1; i < 4; i++) mn = fminf(mn, redbuf[i]);
      atomicMin(&ctrl[0], fkey(mn));
    }
    __syncthreads();
  }
}

// ---- kernel 4: gather + normalize ------------------------------------------
__global__ __launch_bounds__(256) void k_gather(
    const int* __restrict__ rix, const int* __restrict__ cix,
    const float* __restrict__ blocks, const int* __restrict__ ctrl,
    float* __restrict__ out, int n) {
  int i = blockIdx.x * blockDim.x + threadIdx.x;
  if (i >= n) return;
  float m   = funkey(ctrl[0]);
  float M   = funkey(ctrl[1]);
  float inv = 1.0f / (M - m + 1e-7f);
  int r = rix[i], c = cix[i];
  int g = r >> 7;
  float v = blocks[((size_t)g << 14) + ((r & 127) << 7) + (c & 127)];
  out[i] = (v - m) * inv;
}

// ---------------------------------------------------------------------------
extern "C" void kernel_launch(void* const* d_in, const int* in_sizes, int n_in,
                              void* d_out, int out_size, void* d_ws, size_t ws_size,
                              hipStream_t stream) {
  const float* emb = (const float*)d_in[0];
  const int* rix   = (const int*)d_in[1];
  const int* cix   = (const int*)d_in[2];

  char* ws = (char*)d_ws;
  int* ctrl           = (int*)ws;                            // 12 B (pad 256)
  unsigned short* Ebf = (unsigned short*)(ws + 256);         // 16 MB
  char* Eq            = (char*)(ws + 256 + (16u << 20));     // 8 MB
  float* diagblocks   = (float*)(ws + 256 + (24u << 20));    // 8 MB
  int* ipart          = (int*)(ws + 256 + (32u << 20));      // 33 KB

  int n4 = in_sizes[0] / 4;            // 16384*512 / 4

  k_convert<<<(n4 + 255) / 256, 256, 0, stream>>>(emb, Ebf, Eq, ctrl, n4);

  k_gemm<<<dim3(GX, 128), 512, 0, stream>>>(Eq, Ebf, ipart, diagblocks, ctrl);

  k_refine<<<NPAIRIDX, 256, 0, stream>>>(Ebf, ipart, ctrl);

  k_gather<<<(out_size + 255) / 256, 256, 0, stream>>>(rix, cix, diagblocks,
                                                       ctrl, (float*)d_out,
                                                       out_size);
}

// Round 12
// 191.188 us; speedup vs baseline: 1.0774x; 1.0045x over previous
//
#include <hip/hip_runtime.h>
#include <hip/hip_bf16.h>
#include <stdint.h>

// ---------------------------------------------------------------------------
// LinkPredictor: out = minmax_norm(E @ E^T)[block-diag strict upper triangle]
// N=16384 (128 graphs x 128), D=512.
// R22: the last untested cell -- counted-vmcnt pipeline x high occupancy.
// Evidence: counted vmcnt was only tested at 2 waves/SIMD (R15: null --
// nothing to cover with); 4 waves/SIMD was only tested with drain-to-0
// 2-phase (R17: null -- nothing flows past the drain). Catalog's T-stack
// lesson: these gate each other. This round: R17 geometry (512thr, 112 regs,
// 4 waves/SIMD, 2 blocks/CU) + R15's verified protocol (3x24KB buffers,
// prefetch kt+2, s_waitcnt vmcnt(3) at tile bounds -- never 0 until kt==6,
// raw s_barrier + sched_barrier(0) fences, setprio(1) around MFMA).
// Accounting (3 loads/thread/tile): prologue stages t0,t1 (6 outstanding),
// vmcnt(3) completes t0; loop kt stages t(kt+2) (6 outstanding at boundary),
// vmcnt(3) completes t(kt+1), t(kt+2) stays in flight ACROSS the barrier;
// kt==6 boundary: vmcnt(0) (only t7's 3 remain). Buffer hazard: write
// (kt+2)%3 while reading kt%3; (kt+2)%3 was last read at kt-1, all reads
// done before the kt-1 barrier. Decision rule: k_gemm 92+-2 again => every
// matrix cell measured-null => declare structural plateau.
// Diag/refine/convert/gather byte-identical to R21 (passing, 192.0us).
// ---------------------------------------------------------------------------

typedef __attribute__((ext_vector_type(8))) __bf16 bf16x8;
typedef __attribute__((ext_vector_type(16))) float floatx16;
typedef __attribute__((ext_vector_type(4))) int intx4;
typedef __attribute__((ext_vector_type(16))) int intx16;

#define AS1 __attribute__((address_space(1)))
#define AS3 __attribute__((address_space(3)))

static constexpr int DIM      = 512;
static constexpr int NTILE    = 128;
static constexpr int GX       = 72;         // padded grid x (multiple of 8)
static constexpr int NPAIRIDX = 65 * 128;   // pair-slot space (x=64 -> diag)
static constexpr float QS     = 19.5f;      // i8 quant scale
static constexpr int MARGIN_I = 3042;       // 8 sims-units * QS^2

// ctrl: [0] fkey_min [1] fkey_max [2] i8 gmin

static __device__ __forceinline__ unsigned short f2bf_rne(float f) {
  unsigned int u = __float_as_uint(f);
  u += 0x7fffu + ((u >> 16) & 1u);
  return (unsigned short)(u >> 16);
}
static __device__ __forceinline__ int fkey(float f) {
  int s = __float_as_int(f);
  return s >= 0 ? s : (s ^ 0x7fffffff);
}
static __device__ __forceinline__ float funkey(int k) {
  return __int_as_float(k >= 0 ? k : (k ^ 0x7fffffff));
}
// bf16 tile, BK=128 (diag): 16 chunks(16B)/row
static __device__ __forceinline__ int swzd(int row, int c16) {
  return c16 ^ (row & 15);
}
// bf16 tile, BK=64 (refine): 8 chunks(16B)/row
static __device__ __forceinline__ int swz8(int row, int c8) {
  return c8 ^ (row & 7);
}
// i8 BK=64 layout helpers: q = swap bits 0,2 (involution)
static __device__ __forceinline__ int qswap(int v) {
  return (v & 0x7A) | ((v & 1) << 2) | ((v >> 2) & 1);
}
static __device__ __forceinline__ int sfun(int row) {
  return (row & 3) ^ ((row >> 3) & 3);
}

// ---- kernel 1: fp32 -> bf16 + i8, init ctrl --------------------------------
__global__ void k_convert(const float* __restrict__ in,
                          unsigned short* __restrict__ bf,
                          char* __restrict__ q,
                          int* __restrict__ ctrl, int n4) {
  int i = blockIdx.x * blockDim.x + threadIdx.x;
  if (i == 0) {
    ctrl[0] = 0x7fffffff; ctrl[1] = (int)0x80000000;
    ctrl[2] = 0x7fffffff;
  }
  if (i >= n4) return;
  float4 v = ((const float4*)in)[i];
  ushort4 o;
  o.x = f2bf_rne(v.x); o.y = f2bf_rne(v.y);
  o.z = f2bf_rne(v.z); o.w = f2bf_rne(v.w);
  ((ushort4*)bf)[i] = o;
  int qx = __float2int_rn(v.x * QS), qy = __float2int_rn(v.y * QS);
  int qz = __float2int_rn(v.z * QS), qw = __float2int_rn(v.w * QS);
  char4 c;
  c.x = (char)min(127, max(-127, qx));
  c.y = (char)min(127, max(-127, qy));
  c.z = (char)min(127, max(-127, qz));
  c.w = (char)min(127, max(-127, qw));
  ((char4*)q)[i] = c;
}

// ---- kernel 2: GEMM --------------------------------------------------------
// grid (72, 128) x 512 threads: x<64 -> i8 pair strip 128x256 at
// (tr=y, tc={2x,2x+1}); x==64 -> bf16 exact diagonal tile tr; x>64 -> pad.
__global__ __launch_bounds__(512, 4) void k_gemm(
    const char* __restrict__ Eq,
    const unsigned short* __restrict__ E,
    int* __restrict__ ipart,
    float* __restrict__ diagblocks,
    int* __restrict__ ctrl) {
  const int x  = blockIdx.x;
  const int tr = blockIdx.y;
  if (x > 64) return;                      // XCD-alignment padding
  const int pi = tr * 65 + x;

  const int tid = threadIdx.x;
  // i8 path: 3 buffers x {A[8KB], B0[8KB], B1[8KB]} = 72 KB -> 2 blocks/CU.
  // Diag path reuses first 32 KB as one bf16 tile.
  __shared__ __align__(16) char smem[3][24576];
  __shared__ float2 redbuf[8];
  __shared__ int iredbuf[8];

  const int w = tid >> 6, lane = tid & 63;
  const int l31 = lane & 31;
  const int kg  = lane >> 5;

  if (x < 64) {
    const int tc1 = 2 * x + 1;
    if (tc1 <= tr) {                 // pair entirely at/below diagonal
      if (tid == 0) ipart[pi] = 0x7fffffff;
      return;
    }
    const int tc0 = (2 * x > tr) ? 2 * x : tc1;   // dup tc1 if tc0 not off-diag

    const int rowA  = tr  * 128;
    const int rowB0 = tc0 * 128;
    const int rowB1 = tc1 * 128;

    // 8-wave decomposition of the 128x256 output: wr = w>>2 (row half),
    // wc = w&3 (64-col quarter; wc>>1 selects B plane, wc&1 the half inside).
    const int wr = w >> 2;
    const int wcq = w & 3;
    const int bplane = 8192 + (wcq >> 1) * 8192;   // B0 or B1 plane offset

    intx16 acc[2][2];                // 64 AGPR
#pragma unroll
    for (int i = 0; i < 2; i++)
#pragma unroll
      for (int j = 0; j < 2; j++)
#pragma unroll
        for (int r = 0; r < 16; r++) acc[i][j][r] = 0;

    // Stage one BK=64 K-tile (A,B0,B1) into buffer bb: 3 loads/thread
    // (512 threads = exactly one 8KB plane each). LDS dest linear (p*16).
    // Granule p = qswap(row)*4 + (c4 ^ sfun(row)): quad q_=p>>2 -> row =
    // qswap(q_) (involution), c4 = (p&3)^sfun(row). Lanes 4k..4k+3 share a
    // row -> one 64B global line per quad (coalesced); bank signature =
    // R10's measured-zero pattern on the read side.
#define STAGE3(bb, kt) do {                                                   \
    int p_   = tid;                                                           \
    int q_   = p_ >> 2;                                                       \
    int row_ = qswap(q_);                                                     \
    int off_ = (kt) * 64 + (((p_ & 3) ^ sfun(row_)) * 16);                    \
    char* d_ = smem[bb] + p_ * 16;                                            \
    __builtin_amdgcn_global_load_lds(                                         \
        (const AS1 unsigned int*)(Eq + (size_t)(rowA + row_) * DIM + off_),   \
        (AS3 unsigned int*)d_, 16, 0, 0);                                     \
    __builtin_amdgcn_global_load_lds(                                         \
        (const AS1 unsigned int*)(Eq + (size_t)(rowB0 + row_) * DIM + off_),  \
        (AS3 unsigned int*)(d_ + 8192), 16, 0, 0);                            \
    __builtin_amdgcn_global_load_lds(                                         \
        (const AS1 unsigned int*)(Eq + (size_t)(rowB1 + row_) * DIM + off_),  \
        (AS3 unsigned int*)(d_ + 16384), 16, 0, 0);                           \
  } while (0)

    const int ra0 = wr * 64 + l31,        ra1 = wr * 64 + 32 + l31;
    const int rb0 = (wcq & 1) * 64 + l31, rb1 = (wcq & 1) * 64 + 32 + l31;
    // per-thread read offsets: byte addr = qswap(row)*64 + ((c4^sfun(row))<<4)
    const int pa0 = qswap(ra0) * 64, sa0 = sfun(ra0);
    const int pa1 = qswap(ra1) * 64, sa1 = sfun(ra1);
    const int pb0 = qswap(rb0) * 64, sb0 = sfun(rb0);
    const int pb1 = qswap(rb1) * 64, sb1 = sfun(rb1);

    // Prologue: tiles 0 and 1 in flight (6 loads/thread). Complete tile 0
    // (vmcnt(3)); tile 1's 3 stay in flight ACROSS the barrier (T4).
    STAGE3(0, 0);
    STAGE3(1, 1);
    asm volatile("s_waitcnt vmcnt(3)" ::: "memory");
    __builtin_amdgcn_s_barrier();
    __builtin_amdgcn_sched_barrier(0);

#pragma unroll
    for (int kt = 0; kt < 8; kt++) {               // K = 512 = 8 * BK(64)
      // Prefetch tile kt+2 into buf[(kt+2)%3] (never the buffer being read,
      // never the one becoming ready at this iteration's end).
      if (kt + 2 < 8) STAGE3((kt + 2) % 3, kt + 2);
      const char* cb = smem[kt % 3];
#pragma unroll
      for (int ks = 0; ks < 2; ks++) {             // 2 k-steps of 32
        const int c = ks * 2 + kg;
        intx4 af0 = *(const intx4*)(cb +           pa0 + ((c ^ sa0) << 4));
        intx4 af1 = *(const intx4*)(cb +           pa1 + ((c ^ sa1) << 4));
        intx4 bf0 = *(const intx4*)(cb + bplane +  pb0 + ((c ^ sb0) << 4));
        intx4 bf1 = *(const intx4*)(cb + bplane +  pb1 + ((c ^ sb1) << 4));
        __builtin_amdgcn_s_setprio(1);
        acc[0][0] = __builtin_amdgcn_mfma_i32_32x32x32_i8(af0, bf0, acc[0][0], 0, 0, 0);
        acc[0][1] = __builtin_amdgcn_mfma_i32_32x32x32_i8(af0, bf1, acc[0][1], 0, 0, 0);
        acc[1][0] = __builtin_amdgcn_mfma_i32_32x32x32_i8(af1, bf0, acc[1][0], 0, 0, 0);
        acc[1][1] = __builtin_amdgcn_mfma_i32_32x32x32_i8(af1, bf1, acc[1][1], 0, 0, 0);
        __builtin_amdgcn_s_setprio(0);
      }
      if (kt < 7) {
        // Make buf[(kt+1)%3] ready. kt<6: outstanding = t(kt+1) 3 + t(kt+2)
        // 3 -> vmcnt(3) completes t(kt+1), leaves t(kt+2) in flight.
        // kt==6: only t7's 3 remain -> vmcnt(0). Never 0 before that.
        __builtin_amdgcn_sched_barrier(0);
        if (kt < 6) { asm volatile("s_waitcnt vmcnt(3)" ::: "memory"); }
        else        { asm volatile("s_waitcnt vmcnt(0)" ::: "memory"); }
        __builtin_amdgcn_s_barrier();
        __builtin_amdgcn_sched_barrier(0);
      }
    }
#undef STAGE3

    int vmin = 0x7fffffff;
#pragma unroll
    for (int ti = 0; ti < 2; ti++)
#pragma unroll
      for (int tj = 0; tj < 2; tj++)
#pragma unroll
        for (int r = 0; r < 16; r++) vmin = min(vmin, acc[ti][tj][r]);
#pragma unroll
    for (int m_ = 32; m_ >= 1; m_ >>= 1)
      vmin = min(vmin, __shfl_xor(vmin, m_));
    if (lane == 0) iredbuf[w] = vmin;
    __syncthreads();
    if (tid == 0) {
      int mn = iredbuf[0];
      for (int i = 1; i < 8; i++) mn = min(mn, iredbuf[i]);
      ipart[pi] = mn;
      atomicMin(&ctrl[2], mn);
    }
  } else {
    // ---- bf16 diagonal path (exact), BK=128, 32 KB of smem, 8 waves ----
    if (tid == 0) ipart[pi] = 0x7fffffff;        // never flagged
    unsigned short* lA = (unsigned short*)&smem[0][0];
    // per-wave 64x32: wr = w>>2 row half, wcq = w&3 col 32-quarter
    const int wr = w >> 2, wcq = w & 3;
    floatx16 acc[2];
#pragma unroll
    for (int t = 0; t < 2; t++)
#pragma unroll
      for (int r = 0; r < 16; r++) acc[t][r] = 0.f;

    const int rowBase = tr * 128;

    for (int kb = 0; kb < 4; kb++) {
      const int kBase = kb * 128;
#pragma unroll
      for (int j = 0; j < 4; j++) {
        int p   = j * 512 + tid;                  // 0..2047 chunk id
        int row = p >> 4, c16 = p & 15;
        int sc = swzd(row, c16);
        const unsigned short* gA =
            E + (size_t)(rowBase + row) * DIM + kBase + sc * 8;
        __builtin_amdgcn_global_load_lds((const AS1 unsigned int*)gA,
                                         (AS3 unsigned int*)(lA + p * 8), 16, 0, 0);
      }
      __syncthreads();

#pragma unroll
      for (int ks = 0; ks < 8; ks++) {
        bf16x8 af[2], bfv;
        const int c16 = ks * 2 + kg;
#pragma unroll
        for (int t = 0; t < 2; t++) {
          int ra = wr * 64 + t * 32 + l31;
          af[t]  = *(const bf16x8*)(lA + ra * 128 + swzd(ra, c16) * 8);
        }
        {
          int rb = wcq * 32 + l31;
          bfv = *(const bf16x8*)(lA + rb * 128 + swzd(rb, c16) * 8);
        }
#pragma unroll
        for (int t = 0; t < 2; t++)
          acc[t] = __builtin_amdgcn_mfma_f32_32x32x16_bf16(
              af[t], bfv, acc[t], 0, 0, 0);
      }
      __syncthreads();
    }

    float vmin = 3.4e38f, vmax = -3.4e38f;
#pragma unroll
    for (int t = 0; t < 2; t++)
#pragma unroll
      for (int r = 0; r < 16; r++) {
        float v = acc[t][r];
        vmin = fminf(vmin, v);
        vmax = fmaxf(vmax, v);
      }
#pragma unroll
    for (int m_ = 32; m_ >= 1; m_ >>= 1) {
      vmin = fminf(vmin, __shfl_xor(vmin, m_));
      vmax = fmaxf(vmax, __shfl_xor(vmax, m_));
    }
    if (lane == 0) redbuf[w] = make_float2(vmin, vmax);
    __syncthreads();
    if (tid == 0) {
      float mn = redbuf[0].x, mx = redbuf[0].y;
      for (int i = 1; i < 8; i++) {
        mn = fminf(mn, redbuf[i].x);
        mx = fmaxf(mx, redbuf[i].y);
      }
      atomicMin(&ctrl[0], fkey(mn));
      atomicMax(&ctrl[1], fkey(mx));  // global max is diagonal (Cauchy-Schwarz)
    }

    float* Bout = diagblocks + (size_t)tr * (128 * 128);
    const int cbase = wcq * 32 + l31;             // C/D: col = lane & 31
#pragma unroll
    for (int t = 0; t < 2; t++) {
#pragma unroll
      for (int r = 0; r < 16; r++) {
        int row = wr * 64 + t * 32 + (r & 3) + 8 * (r >> 2) + 4 * kg;
        Bout[row * 128 + cbase] = acc[t][r];
      }
    }
  }
}

// ---- kernel 3: self-flagged bf16 refine (exact min of flagged pairs) -------
__global__ __launch_bounds__(256) void k_refine(
    const unsigned short* __restrict__ E,
    const int* __restrict__ ipart, int* __restrict__ ctrl) {
  const int pi = blockIdx.x;
  if (ipart[pi] > ctrl[2] + MARGIN_I) return;     // block-uniform
  const int tr = pi / 65, x = pi % 65;
  if (x == 64) return;                            // diag: exact already

  const int tid = threadIdx.x;
  __shared__ __align__(16) unsigned short lA[128 * 64];
  __shared__ __align__(16) unsigned short lB[128 * 64];
  __shared__ float redbuf[4];

  const int w = tid >> 6, lane = tid & 63;
  const int wr = w >> 1, wc = w & 1;
  const int l31 = lane & 31;
  const int kg  = lane >> 5;

  for (int s = 0; s < 2; s++) {
    const int tc = 2 * x + s;
    if (tc <= tr) continue;

    floatx16 acc[2][2];
#pragma unroll
    for (int i = 0; i < 2; i++)
#pragma unroll
      for (int j = 0; j < 2; j++)
#pragma unroll
        for (int r = 0; r < 16; r++) acc[i][j][r] = 0.f;

    const int rowBaseA = tr * 128;
    const int rowBaseB = tc * 128;

    for (int kb = 0; kb < 8; kb++) {              // BK=64
      const int kBase = kb * 64;
#pragma unroll
      for (int j = 0; j < 4; j++) {
        int cb  = (w * 4 + j) * 64;
        int p   = cb + lane;
        int row = p >> 3, c8 = p & 7;
        int sc8 = swz8(row, c8);
        const unsigned short* gA = E + (size_t)(rowBaseA + row) * DIM + kBase + sc8 * 8;
        const unsigned short* gB = E + (size_t)(rowBaseB + row) * DIM + kBase + sc8 * 8;
        __builtin_amdgcn_global_load_lds((const AS1 unsigned int*)gA,
                                         (AS3 unsigned int*)(lA + cb * 8), 16, 0, 0);
        __builtin_amdgcn_global_load_lds((const AS1 unsigned int*)gB,
                                         (AS3 unsigned int*)(lB + cb * 8), 16, 0, 0);
      }
      __syncthreads();

#pragma unroll
      for (int ks = 0; ks < 4; ks++) {
        bf16x8 af[2], bfv[2];
        const int c8 = ks * 2 + kg;
#pragma unroll
        for (int t = 0; t < 2; t++) {
          int ra = wr * 64 + t * 32 + l31;
          int rb = wc * 64 + t * 32 + l31;
          af[t]  = *(const bf16x8*)(lA + (ra * 8 + swz8(ra, c8)) * 8);
          bfv[t] = *(const bf16x8*)(lB + (rb * 8 + swz8(rb, c8)) * 8);
        }
#pragma unroll
        for (int ti = 0; ti < 2; ti++)
#pragma unroll
          for (int tj = 0; tj < 2; tj++)
            acc[ti][tj] = __builtin_amdgcn_mfma_f32_32x32x16_bf16(
                af[ti], bfv[tj], acc[ti][tj], 0, 0, 0);
      }
      __syncthreads();
    }

    float vmin = 3.4e38f;
#pragma unroll
    for (int ti = 0; ti < 2; ti++)
#pragma unroll
      for (int tj = 0; tj < 2; tj++)
#pragma unroll
        for (int r = 0; r < 16; r++) vmin = fminf(vmin, acc[ti][tj][r]);
#pragma unroll
    for (int m_ = 32; m_ >= 1; m_ >>= 1)
      vmin = fminf(vmin, __shfl_xor(vmin, m_));
    if (lane == 0) redbuf[w] = vmin;
    __syncthreads();
    if (tid == 0) {
      float mn = redbuf[0];
      for (int i = 1; i < 4; i++) mn = fminf(mn, redbuf[i]);
      atomicMin(&ctrl[0], fkey(mn));
    }
    __syncthreads();
  }
}

// ---- kernel 4: gather + normalize ------------------------------------------
__global__ __launch_bounds__(256) void k_gather(
    const int* __restrict__ rix, const int* __restrict__ cix,
    const float* __restrict__ blocks, const int* __restrict__ ctrl,
    float* __restrict__ out, int n) {
  int i = blockIdx.x * blockDim.x + threadIdx.x;
  if (i >= n) return;
  float m   = funkey(ctrl[0]);
  float M   = funkey(ctrl[1]);
  float inv = 1.0f / (M - m + 1e-7f);
  int r = rix[i], c = cix[i];
  int g = r >> 7;
  float v = blocks[((size_t)g << 14) + ((r & 127) << 7) + (c & 127)];
  out[i] = (v - m) * inv;
}

// ---------------------------------------------------------------------------
extern "C" void kernel_launch(void* const* d_in, const int* in_sizes, int n_in,
                              void* d_out, int out_size, void* d_ws, size_t ws_size,
                              hipStream_t stream) {
  const float* emb = (const float*)d_in[0];
  const int* rix   = (const int*)d_in[1];
  const int* cix   = (const int*)d_in[2];

  char* ws = (char*)d_ws;
  int* ctrl           = (int*)ws;                            // 12 B (pad 256)
  unsigned short* Ebf = (unsigned short*)(ws + 256);         // 16 MB
  char* Eq            = (char*)(ws + 256 + (16u << 20));     // 8 MB
  float* diagblocks   = (float*)(ws + 256 + (24u << 20));    // 8 MB
  int* ipart          = (int*)(ws + 256 + (32u << 20));      // 33 KB

  int n4 = in_sizes[0] / 4;            // 16384*512 / 4

  k_convert<<<(n4 + 255) / 256, 256, 0, stream>>>(emb, Ebf, Eq, ctrl, n4);

  k_gemm<<<dim3(GX, 128), 512, 0, stream>>>(Eq, Ebf, ipart, diagblocks, ctrl);

  k_refine<<<NPAIRIDX, 256, 0, stream>>>(Ebf, ipart, ctrl);

  k_gather<<<(out_size + 255) / 256, 256, 0, stream>>>(rix, cix, diagblocks,
                                                       ctrl, (float*)d_out,
                                                       out_size);
}